// Round 3
// baseline (171.130 us; speedup 1.0000x reference)
//
#include <hip/hip_runtime.h>

#define N_NODES 8192
#define D_IN 512
#define D_OUT 64
#define LRELU_ALPHA 0.2f

// ---------------- Kernel 1: Wh = h @ W, fused Wh1/Wh2 epilogue ----------------
__global__ __launch_bounds__(256) void k_gemm_wh(const float* __restrict__ h,
                                                 const float* __restrict__ W,
                                                 const float* __restrict__ a,
                                                 float* __restrict__ Wh,
                                                 float* __restrict__ Wh1,
                                                 float* __restrict__ Wh2) {
    __shared__ float hs[32][68];
    __shared__ float Ws[64][64];
    const int tid = threadIdx.x;
    const int r0 = blockIdx.x * 32;
    const int tf = tid & 15;   // feature group: f = tf*4 .. tf*4+3
    const int tr = tid >> 4;   // row group: rows tr*2, tr*2+1
    float acc[2][4] = {{0.f,0.f,0.f,0.f},{0.f,0.f,0.f,0.f}};

    for (int kc = 0; kc < D_IN; kc += 64) {
        {
            int rr = tid >> 4;
            int cc = (tid & 15) * 4;
            float4 v0 = *(const float4*)&h[(size_t)(r0 + rr) * D_IN + kc + cc];
            float4 v1 = *(const float4*)&h[(size_t)(r0 + rr + 16) * D_IN + kc + cc];
            *(float4*)&hs[rr][cc] = v0;
            *(float4*)&hs[rr + 16][cc] = v1;
        }
        #pragma unroll
        for (int p = 0; p < 4; ++p) {
            int kk = (tid >> 4) + p * 16;
            int cc = (tid & 15) * 4;
            *(float4*)&Ws[kk][cc] = *(const float4*)&W[(size_t)(kc + kk) * D_OUT + cc];
        }
        __syncthreads();
        #pragma unroll
        for (int k = 0; k < 64; k += 4) {
            float4 a0 = *(const float4*)&hs[tr*2][k];
            float4 a1 = *(const float4*)&hs[tr*2+1][k];
            float av0[4] = {a0.x, a0.y, a0.z, a0.w};
            float av1[4] = {a1.x, a1.y, a1.z, a1.w};
            #pragma unroll
            for (int kk = 0; kk < 4; ++kk) {
                float4 b = *(const float4*)&Ws[k+kk][tf*4];
                acc[0][0] += av0[kk]*b.x; acc[0][1] += av0[kk]*b.y;
                acc[0][2] += av0[kk]*b.z; acc[0][3] += av0[kk]*b.w;
                acc[1][0] += av1[kk]*b.x; acc[1][1] += av1[kk]*b.y;
                acc[1][2] += av1[kk]*b.z; acc[1][3] += av1[kk]*b.w;
            }
        }
        __syncthreads();
    }
    const int orow = r0 + tr*2;
    *(float4*)&Wh[(size_t)orow * D_OUT + tf*4]     = make_float4(acc[0][0], acc[0][1], acc[0][2], acc[0][3]);
    *(float4*)&Wh[(size_t)(orow+1) * D_OUT + tf*4] = make_float4(acc[1][0], acc[1][1], acc[1][2], acc[1][3]);

    // fused epilogue: Wh1[row] = Wh[row]·a[:64], Wh2[row] = Wh[row]·a[64:]
    float a1v[4], a2v[4];
    #pragma unroll
    for (int k = 0; k < 4; ++k) { a1v[k] = a[tf*4 + k]; a2v[k] = a[64 + tf*4 + k]; }
    float s1 = 0.f, t1 = 0.f, s2 = 0.f, t2 = 0.f;
    #pragma unroll
    for (int k = 0; k < 4; ++k) {
        s1 += acc[0][k] * a1v[k];
        t1 += acc[1][k] * a1v[k];
        s2 += acc[0][k] * a2v[k];
        t2 += acc[1][k] * a2v[k];
    }
    #pragma unroll
    for (int d = 1; d < 16; d <<= 1) {
        s1 += __shfl_xor(s1, d);
        t1 += __shfl_xor(t1, d);
        s2 += __shfl_xor(s2, d);
        t2 += __shfl_xor(t2, d);
    }
    if (tf == 0) {
        Wh1[orow] = s1; Wh1[orow + 1] = t1;
        Wh2[orow] = s2; Wh2[orow + 1] = t2;
    }
}

// ---------------- Kernel 2: one WAVE = one row; zero LDS, zero barriers ----------------
// Lane f owns out[row][f]. Scan row's mask (+Wh2) as float4; per component the ballot
// gives a wave-uniform SGPR bitmask; drain set bits serially in a uniform loop:
// s_ff1 -> j (SGPR), v_readlane broadcasts Wh2[j], online-softmax (uniform rescale
// branch, ~6x per row), one coalesced 256B Wh[j] row load + FMA per entry. Dual-entry
// unroll keeps 2 row loads in flight. No cross-lane reduction needed at the end.
__global__ __launch_bounds__(256) void k_attn(const float* __restrict__ mask,
                                              const float* __restrict__ Wh,
                                              const float* __restrict__ Wh1,
                                              const float* __restrict__ Wh2,
                                              float* __restrict__ out) {
    const int wave = threadIdx.x >> 6;
    const int lane = threadIdx.x & 63;
    const int row = blockIdx.x * 4 + wave;
    const float wh1 = Wh1[row];

    const float4* mask4 = (const float4*)(mask + (size_t)row * N_NODES);
    const float4* wh24  = (const float4*)Wh2;

    float accf = 0.f;        // per-lane: feature `lane` of the output row
    float lsum = 0.f;        // lane-uniform softmax denominator
    float m_run = -3.0e38f;  // lane-uniform running max

    for (int it = 0; it < 32; ++it) {
        const int q = it * 64 + lane;
        const float4 mk = mask4[q];
        const float4 w2 = wh24[q];
        const int base = it * 256;
        const float mkv[4] = {mk.x, mk.y, mk.z, mk.w};
        const int   w2b[4] = {__float_as_int(w2.x), __float_as_int(w2.y),
                              __float_as_int(w2.z), __float_as_int(w2.w)};
        #pragma unroll
        for (int c = 0; c < 4; ++c) {
            unsigned long long b = __ballot(mkv[c] > 0.f);
            while (b) {
                const int bit0 = __builtin_ctzll(b); b &= b - 1;
                const float w2_0 = __int_as_float(__builtin_amdgcn_readlane(w2b[c], bit0));
                const float v0 = Wh[(size_t)(base + (bit0 << 2) + c) * D_OUT + lane];
                if (b) {
                    const int bit1 = __builtin_ctzll(b); b &= b - 1;
                    const float w2_1 = __int_as_float(__builtin_amdgcn_readlane(w2b[c], bit1));
                    const float v1 = Wh[(size_t)(base + (bit1 << 2) + c) * D_OUT + lane];
                    float e0 = wh1 + w2_0; e0 = fmaxf(e0, LRELU_ALPHA * e0);
                    float e1 = wh1 + w2_1; e1 = fmaxf(e1, LRELU_ALPHA * e1);
                    const float em = fmaxf(e0, e1);
                    if (em > m_run) {
                        const float s = __expf(m_run - em);
                        accf *= s; lsum *= s; m_run = em;
                    }
                    const float p0 = __expf(e0 - m_run);
                    const float p1 = __expf(e1 - m_run);
                    lsum += p0 + p1;
                    accf += p0 * v0;
                    accf += p1 * v1;
                } else {
                    float e0 = wh1 + w2_0; e0 = fmaxf(e0, LRELU_ALPHA * e0);
                    if (e0 > m_run) {
                        const float s = __expf(m_run - e0);
                        accf *= s; lsum *= s; m_run = e0;
                    }
                    const float p0 = __expf(e0 - m_run);
                    lsum += p0;
                    accf += p0 * v0;
                }
            }
        }
    }

    if (lsum == 0.f) {
        // all-masked row: softmax over uniform -9e15 = 1/N -> mean of Wh rows
        float s = 0.f;
        for (int j = 0; j < N_NODES; ++j) s += Wh[(size_t)j * D_OUT + lane];
        accf = s; lsum = (float)N_NODES;
    }

    const float v = accf / lsum;
    out[(size_t)row * D_OUT + lane] = (v > 0.f) ? v : (__expf(v) - 1.f);
}

extern "C" void kernel_launch(void* const* d_in, const int* in_sizes, int n_in,
                              void* d_out, int out_size, void* d_ws, size_t ws_size,
                              hipStream_t stream) {
    const float* h    = (const float*)d_in[0];
    const float* mask = (const float*)d_in[1];
    // d_in[2] = lamda: unused (dischange==0 makes the mask-update a no-op)
    const float* W    = (const float*)d_in[3];
    const float* a    = (const float*)d_in[4];
    float* out = (float*)d_out;

    float* Wh  = (float*)d_ws;
    float* Wh1 = Wh + (size_t)N_NODES * D_OUT;
    float* Wh2 = Wh1 + N_NODES;

    k_gemm_wh<<<N_NODES / 32, 256, 0, stream>>>(h, W, a, Wh, Wh1, Wh2);
    k_attn<<<N_NODES / 4, 256, 0, stream>>>(mask, Wh, Wh1, Wh2, out);
}